// Round 10
// baseline (285.192 us; speedup 1.0000x reference)
//
#include <hip/hip_runtime.h>
#include <hip/hip_bf16.h>

// Conv 3x3 s1 p1, N=32 CIN=128 H=W=56 COUT=256, fp32 in/out, bf16 MFMA implicit GEMM.
// R5: gemm restructured — A (weights, 576KB, L2-hot) read direct global->VGPR;
//     B (xt pixels) in LDS, double-buffered 2x16KB; one __syncthreads per K-step
//     (counted-2ph: stage issued BEFORE compute, drained at the post-compute barrier).
//     xconv / wreorder unchanged from R4.

typedef __attribute__((ext_vector_type(8))) short bf16x8;
typedef __attribute__((ext_vector_type(4))) float f32x4;
typedef __attribute__((ext_vector_type(8))) unsigned short u16x8;

#define AS1(p) ((const __attribute__((address_space(1))) unsigned int*)(p))
#define AS3(p) ((__attribute__((address_space(3))) unsigned int*)(p))
#define G_LDS16(g, l) __builtin_amdgcn_global_load_lds(AS1(g), AS3(l), 16, 0, 0)

#define XT_OFF (1u << 20)

// ---- weight reorder: wt[(khkw*256+co)*128+ci] = w[(co*128+ci)*9+khkw] ----
__global__ __launch_bounds__(256) void k_wreorder(const float* __restrict__ w,
                                                  __hip_bfloat16* __restrict__ wt) {
    int t = blockIdx.x * 256 + threadIdx.x;     // 9*256*128 = 294,912 total
    if (t >= 9 * 256 * 128) return;
    int ci = t & 127;
    int co = (t >> 7) & 255;
    int khkw = t >> 15;
    wt[t] = __float2bfloat16(w[(co * 128 + ci) * 9 + khkw]);
}

// ---- x NCHW fp32 -> xt [n][ih=58][iw=58][ci=128] bf16, halo included ----
__global__ __launch_bounds__(256) void k_xconv(const float* __restrict__ x,
                                               __hip_bfloat16* __restrict__ xt) {
    const int b = blockIdx.x;                 // n*58 + ih
    const int n = b / 58, ih = b % 58;
    __hip_bfloat16* row = xt + (size_t)b * 58 * 128;
    const int t = threadIdx.x;

    if (ih == 0 || ih == 57) {                // top/bottom halo row: all zeros
        u16x8 z = {0, 0, 0, 0, 0, 0, 0, 0};
        for (int i = t; i < 928; i += 256)    // 58*128*2B / 16B
            ((u16x8*)row)[i] = z;
        return;
    }

    const int h = ih - 1;
    __shared__ float tile[56][132];           // [w][ci], stride 132
    const float* xb = x + (size_t)n * 128 * 3136 + h * 56;
    for (int i = t; i < 1792; i += 256) {     // 128 ci-rows x 14 float4
        int ci = i / 14, w4 = i % 14;
        f32x4 v = *(const f32x4*)(xb + ci * 3136 + w4 * 4);
#pragma unroll
        for (int c = 0; c < 4; ++c)
            tile[w4 * 4 + c][ci] = v[c];
    }
    __syncthreads();

    if (t < 32) {                             // left/right halo columns: zeros
        u16x8 z = {0, 0, 0, 0, 0, 0, 0, 0};
        int iw = (t < 16) ? 0 : 57;
        ((u16x8*)(row + iw * 128))[t & 15] = z;
    }
    for (int i = t; i < 896; i += 256) {      // 56 px x 16 chunks (coalesced)
        int p = i >> 4, g = i & 15;
        u16x8 o;
#pragma unroll
        for (int j = 0; j < 8; ++j) {
            __hip_bfloat16 bv = __float2bfloat16(tile[p][g * 8 + j]);
            o[j] = *reinterpret_cast<unsigned short*>(&bv);
        }
        *(u16x8*)((char*)row + (p + 1) * 256 + g * 16) = o;
    }
}

// ---- implicit GEMM: 256 co x 128 px, K = 18 steps of 64 ci ----
// A-frags direct from global (wt is L1/L2-hot); B in LDS dbuf 2x16KB.
__global__ __launch_bounds__(512, 2) void k_conv_gemm(
    const __hip_bfloat16* __restrict__ wt,   // [9][256][128]
    const __hip_bfloat16* __restrict__ xt,   // [32][58][58][128]
    const float* __restrict__ bias,          // [256]
    float* __restrict__ out)                 // [32][256][56][56]
{
    __shared__ char ldsB[2][128 * 128];      // 2 x 16 KiB (px rows x 128B)

    // XCD-bijective swizzle: 784 blocks = 8 * 98
    const int bid = blockIdx.x;
    const int blk = (bid & 7) * 98 + (bid >> 3);

    const int tid = threadIdx.x;
    const int lane = tid & 63, wave = tid >> 6;
    const int co_w = (wave >> 1) * 64;       // wave's co base (0/64/128/192)
    const int px_w = (wave & 1) * 64;        // wave's px base (0/64)

    const int lr = lane >> 3;                // staging row within 8-row group
    const int lc = lane & 7;                 // 16B chunk within 128B row
    const int swz = ((lc ^ lr) << 4);        // T2 pre-swizzled source chunk

    // per-lane B-staging source bases (pixel geometry fixed across K-loop)
    unsigned int bsrc[2];
#pragma unroll
    for (int r = 0; r < 2; ++r) {
        int px = r * 64 + wave * 8 + lr;
        int p = blk * 128 + px;
        int n = p / 3136, rem = p - n * 3136;
        int oh = rem / 56, ow = rem - oh * 56;
        bsrc[r] = (unsigned)(((n * 58 + oh) * 58 + ow) * 256) + swz;
    }

    // per-lane A base: co row + k chunk (add m*4096 + khalf*64 + cih*128 + khkw*65536)
    const unsigned abase = (unsigned)((co_w + (lane & 15)) * 256 + (lane >> 4) * 16);

    f32x4 acc[4][4] = {};

    // prologue: stage step 0 into buf 0
    {
#pragma unroll
        for (int r = 0; r < 2; ++r)
            G_LDS16((const char*)xt + bsrc[r] + /*kh=0,kw=0*/ 0 + /*cih*/ 0,
                    ldsB[0] + (r * 64 + wave * 8) * 128);
    }
    __syncthreads();

    int cur = 0;
    for (int step = 0; step < 18; ++step) {
        // issue next-step B stage into the other buffer (hidden under compute)
        if (step + 1 < 18) {
            int s = step + 1;
            int kk = s >> 1, cih = s & 1;
            int kh = kk / 3, kw = kk - kh * 3;
            unsigned off = (unsigned)((kh * 58 + kw) * 256 + cih * 128);
#pragma unroll
            for (int r = 0; r < 2; ++r)
                G_LDS16((const char*)xt + bsrc[r] + off,
                        ldsB[cur ^ 1] + (r * 64 + wave * 8) * 128);
        }

        const int kk = step >> 1, cih = step & 1;
        const unsigned aoff = (unsigned)(kk * 65536 + cih * 128) + abase;

#pragma unroll
        for (int khalf = 0; khalf < 2; ++khalf) {
            bf16x8 af[4], bx[4];
#pragma unroll
            for (int m = 0; m < 4; ++m)
                af[m] = *(const bf16x8*)((const char*)wt + aoff + m * 4096 + khalf * 64);
#pragma unroll
            for (int nn = 0; nn < 4; ++nn) {
                int row = px_w + nn * 16 + (lane & 15);
                int koff = (khalf * 64 + ((lane >> 4) * 16)) ^ ((row & 7) << 4);
                bx[nn] = *(const bf16x8*)(ldsB[cur] + row * 128 + koff);
            }
#pragma unroll
            for (int m = 0; m < 4; ++m)
#pragma unroll
                for (int nn = 0; nn < 4; ++nn)
                    acc[m][nn] = __builtin_amdgcn_mfma_f32_16x16x32_bf16(
                        af[m], bx[nn], acc[m][nn], 0, 0, 0);
        }
        __syncthreads();     // drains this iter's stage loads; publishes buf^1
        cur ^= 1;
    }

    // epilogue: D col = px = lane&15 (+nn*16+px_w), D row = co = (lane>>4)*4 + r
    int obase[4];
#pragma unroll
    for (int nn = 0; nn < 4; ++nn) {
        int p = blk * 128 + px_w + nn * 16 + (lane & 15);
        int n = p / 3136, rem = p - n * 3136;
        obase[nn] = n * 802816 + rem;        // + co*3136 gives out index
    }
    const int rgrp = lane >> 4;
#pragma unroll
    for (int m = 0; m < 4; ++m) {
#pragma unroll
        for (int r = 0; r < 4; ++r) {
            int co = co_w + m * 16 + rgrp * 4 + r;
            float bv = bias[co];
#pragma unroll
            for (int nn = 0; nn < 4; ++nn)
                out[obase[nn] + co * 3136] = acc[m][nn][r] + bv;
        }
    }
}

extern "C" void kernel_launch(void* const* d_in, const int* in_sizes, int n_in,
                              void* d_out, int out_size, void* d_ws, size_t ws_size,
                              hipStream_t stream) {
    const float* x    = (const float*)d_in[0];
    const float* w    = (const float*)d_in[1];
    const float* bias = (const float*)d_in[2];
    float* out = (float*)d_out;

    char* ws = (char*)d_ws;
    __hip_bfloat16* wt = (__hip_bfloat16*)ws;
    __hip_bfloat16* xt = (__hip_bfloat16*)(ws + XT_OFF);

    k_wreorder<<<1152, 256, 0, stream>>>(w, wt);
    k_xconv<<<32 * 58, 256, 0, stream>>>(x, xt);
    k_conv_gemm<<<784, 512, 0, stream>>>(wt, xt, bias, out);
}

// Round 11
// 213.154 us; speedup vs baseline: 1.3380x; 1.3380x over previous
//
#include <hip/hip_runtime.h>
#include <hip/hip_bf16.h>

// Conv 3x3 s1 p1, N=32 CIN=128 H=W=56 COUT=256, fp32 in/out, bf16 MFMA implicit GEMM.
// R6: revert R5's A-direct (vmcnt poisoning, MfmaUtil 14.6%). Tri-buffered K-pipeline:
//     slot = A(256x64ci, 32KB) + B(128px x 64ci, 16KB) = 48KB; 3 slots = 144KB LDS.
//     Per K-step: vmcnt(6) -> s_barrier -> stage(t+2) -> ds_read(t) -> 32 MFMA.
//     Counted vmcnt never drains to 0 in-loop (T4); staging leads by 2 K-tiles.
//     Tile 256co x 128px, 8 waves (4M x 2N), each 64x64 out. T2 swizzle as R4 (0 conflicts).

typedef __attribute__((ext_vector_type(8))) short bf16x8;
typedef __attribute__((ext_vector_type(4))) float f32x4;
typedef __attribute__((ext_vector_type(8))) unsigned short u16x8;

#define AS1(p) ((const __attribute__((address_space(1))) unsigned int*)(p))
#define AS3(p) ((__attribute__((address_space(3))) unsigned int*)(p))
#define G_LDS16(g, l) __builtin_amdgcn_global_load_lds(AS1(g), AS3(l), 16, 0, 0)

#define XT_OFF (1u << 20)

// ---- weight reorder: wt[(khkw*256+co)*128+ci] = w[(co*128+ci)*9+khkw] ----
__global__ __launch_bounds__(256) void k_wreorder(const float* __restrict__ w,
                                                  __hip_bfloat16* __restrict__ wt) {
    int t = blockIdx.x * 256 + threadIdx.x;
    if (t >= 9 * 256 * 128) return;
    int ci = t & 127;
    int co = (t >> 7) & 255;
    int khkw = t >> 15;
    wt[t] = __float2bfloat16(w[(co * 128 + ci) * 9 + khkw]);
}

// ---- x NCHW fp32 -> xt [n][ih=58][iw=58][ci=128] bf16, halo included ----
__global__ __launch_bounds__(256) void k_xconv(const float* __restrict__ x,
                                               __hip_bfloat16* __restrict__ xt) {
    const int b = blockIdx.x;                 // n*58 + ih
    const int n = b / 58, ih = b % 58;
    __hip_bfloat16* row = xt + (size_t)b * 58 * 128;
    const int t = threadIdx.x;

    if (ih == 0 || ih == 57) {
        u16x8 z = {0, 0, 0, 0, 0, 0, 0, 0};
        for (int i = t; i < 928; i += 256)
            ((u16x8*)row)[i] = z;
        return;
    }

    const int h = ih - 1;
    __shared__ float tile[56][132];
    const float* xb = x + (size_t)n * 128 * 3136 + h * 56;
    for (int i = t; i < 1792; i += 256) {
        int ci = i / 14, w4 = i % 14;
        f32x4 v = *(const f32x4*)(xb + ci * 3136 + w4 * 4);
#pragma unroll
        for (int c = 0; c < 4; ++c)
            tile[w4 * 4 + c][ci] = v[c];
    }
    __syncthreads();

    if (t < 32) {
        u16x8 z = {0, 0, 0, 0, 0, 0, 0, 0};
        int iw = (t < 16) ? 0 : 57;
        ((u16x8*)(row + iw * 128))[t & 15] = z;
    }
    for (int i = t; i < 896; i += 256) {
        int p = i >> 4, g = i & 15;
        u16x8 o;
#pragma unroll
        for (int j = 0; j < 8; ++j) {
            __hip_bfloat16 bv = __float2bfloat16(tile[p][g * 8 + j]);
            o[j] = *reinterpret_cast<unsigned short*>(&bv);
        }
        *(u16x8*)((char*)row + (p + 1) * 256 + g * 16) = o;
    }
}

// ---- implicit GEMM: 256 co x 128 px, K = 18 steps of 64 ci, tri-buffered ----
__global__ __launch_bounds__(512, 2) void k_conv_gemm(
    const __hip_bfloat16* __restrict__ wt,   // [9][256][128]
    const __hip_bfloat16* __restrict__ xt,   // [32][58][58][128]
    const float* __restrict__ bias,          // [256]
    float* __restrict__ out)                 // [32][256][56][56]
{
    // slot: [A rows 0..255][B rows 256..383], each row 128 B. 48 KiB per slot.
    __shared__ char lds[3][384 * 128];

    // XCD-bijective swizzle: 784 blocks = 8 * 98
    const int bid = blockIdx.x;
    const int blk = (bid & 7) * 98 + (bid >> 3);

    const int tid = threadIdx.x;
    const int lane = tid & 63, wave = tid >> 6;
    const int wm = wave >> 1;                // 0..3 : co quadrant (64 rows)
    const int wn = wave & 1;                 // 0..1 : px half (64 px)

    const int lr = lane >> 3;                // staging row within 8-row group
    const int lc = lane & 7;                 // 16B chunk within 128B row
    const int swz = ((lc ^ lr) << 4);        // T2 pre-swizzled source chunk

    // per-lane B staging source bases (pixel geometry fixed across K-loop)
    unsigned int bsrc[2];
#pragma unroll
    for (int r = 0; r < 2; ++r) {
        int px = r * 64 + wave * 8 + lr;
        int p = blk * 128 + px;
        int n = p / 3136, rem = p - n * 3136;
        int oh = rem / 56, ow = rem - oh * 56;
        bsrc[r] = (unsigned)(((n * 58 + oh) * 58 + ow) * 256) + swz;
    }

    // stage K-tile s into slot: 4 A-rounds + 2 B-rounds = 6 G_LDS16 / thread
    auto stage = [&](int s, char* slot) {
        const int kk = s >> 1, cih = s & 1;
        const int kh = kk / 3, kw = kk - kh * 3;
        const unsigned aoff = (unsigned)(kk * 65536 + cih * 128);
#pragma unroll
        for (int r = 0; r < 4; ++r) {
            int row = r * 64 + wave * 8;     // + lr implicit via lane*16
            G_LDS16((const char*)wt + aoff + (row + lr) * 256 + swz,
                    slot + row * 128);
        }
        const unsigned boff = (unsigned)((kh * 58 + kw) * 256 + cih * 128);
#pragma unroll
        for (int r = 0; r < 2; ++r) {
            G_LDS16((const char*)xt + bsrc[r] + boff,
                    slot + (256 + r * 64 + wave * 8) * 128);
        }
    };

    f32x4 acc[4][4] = {};

    stage(0, lds[0]);
    stage(1, lds[1]);

    char* cs = lds[0];   // compute slot (t)
    char* ns = lds[1];   // next slot (t+1)
    char* ps = lds[2];   // prefetch dest (t+2); == slot read at t-1, safe after barrier

    for (int t = 0; t < 18; ++t) {
        // counted wait: all loads older than the newest 6 (= tile t+1's stage) done
        if (t < 17) asm volatile("s_waitcnt vmcnt(6)" ::: "memory");
        else        asm volatile("s_waitcnt vmcnt(0)" ::: "memory");
        __builtin_amdgcn_s_barrier();
        __builtin_amdgcn_sched_barrier(0);

        if (t < 16) stage(t + 2, ps);

        bf16x8 af[2][4], bx[2][4];
#pragma unroll
        for (int kh2 = 0; kh2 < 2; ++kh2) {
#pragma unroll
            for (int m = 0; m < 4; ++m) {
                int row = wm * 64 + m * 16 + (lane & 15);
                int koff = (kh2 * 64 + ((lane >> 4) * 16)) ^ ((row & 7) << 4);
                af[kh2][m] = *(const bf16x8*)(cs + row * 128 + koff);
            }
#pragma unroll
            for (int nn = 0; nn < 4; ++nn) {
                int row = wn * 64 + nn * 16 + (lane & 15);
                int koff = (kh2 * 64 + ((lane >> 4) * 16)) ^ ((row & 7) << 4);
                bx[kh2][nn] = *(const bf16x8*)(cs + (256 + row) * 128 + koff);
            }
        }

        __builtin_amdgcn_s_setprio(1);
#pragma unroll
        for (int kh2 = 0; kh2 < 2; ++kh2)
#pragma unroll
            for (int m = 0; m < 4; ++m)
#pragma unroll
                for (int nn = 0; nn < 4; ++nn)
                    acc[m][nn] = __builtin_amdgcn_mfma_f32_16x16x32_bf16(
                        af[kh2][m], bx[kh2][nn], acc[m][nn], 0, 0, 0);
        __builtin_amdgcn_s_setprio(0);

        char* tmp = cs; cs = ns; ns = ps; ps = tmp;   // rotate slots
    }

    // epilogue: D col = px = lane&15, D row = co = (lane>>4)*4 + r
    int obase[4];
#pragma unroll
    for (int nn = 0; nn < 4; ++nn) {
        int p = blk * 128 + wn * 64 + nn * 16 + (lane & 15);
        int n = p / 3136, rem = p - n * 3136;
        obase[nn] = n * 802816 + rem;
    }
    const int rgrp = lane >> 4;
#pragma unroll
    for (int m = 0; m < 4; ++m) {
#pragma unroll
        for (int r = 0; r < 4; ++r) {
            int co = wm * 64 + m * 16 + rgrp * 4 + r;
            float bv = bias[co];
#pragma unroll
            for (int nn = 0; nn < 4; ++nn)
                out[obase[nn] + co * 3136] = acc[m][nn][r] + bv;
        }
    }
}

extern "C" void kernel_launch(void* const* d_in, const int* in_sizes, int n_in,
                              void* d_out, int out_size, void* d_ws, size_t ws_size,
                              hipStream_t stream) {
    const float* x    = (const float*)d_in[0];
    const float* w    = (const float*)d_in[1];
    const float* bias = (const float*)d_in[2];
    float* out = (float*)d_out;

    char* ws = (char*)d_ws;
    __hip_bfloat16* wt = (__hip_bfloat16*)ws;
    __hip_bfloat16* xt = (__hip_bfloat16*)(ws + XT_OFF);

    k_wreorder<<<1152, 256, 0, stream>>>(w, wt);
    k_xconv<<<32 * 58, 256, 0, stream>>>(x, xt);
    k_conv_gemm<<<784, 512, 0, stream>>>(wt, xt, bias, out);
}